// Round 10
// baseline (4159.314 us; speedup 1.0000x reference)
//
#include <hip/hip_runtime.h>
#include <math.h>

#define H_ 12
#define STEPS_ 12
#define ALPHA_ 0.1f
#define EPS_ 1e-5f
#define BETA_ 0.125f          // 1/sqrt(64)
#define NTOK 8192

typedef unsigned short u16;
typedef __attribute__((ext_vector_type(8))) u16 u16x8;
typedef __attribute__((ext_vector_type(4))) u16 u16x4;
typedef __attribute__((ext_vector_type(4))) float f32x4;
typedef __attribute__((ext_vector_type(8))) __bf16 bf16x8;

#define MFMA __builtin_amdgcn_mfma_f32_16x16x32_bf16

__device__ __forceinline__ u16 f2bf(float x) {
    unsigned u = __float_as_uint(x);
    u += 0x7FFFu + ((u >> 16) & 1u);
    return (u16)(u >> 16);
}
__device__ __forceinline__ float bf2f(u16 u) {
    return __uint_as_float(((unsigned)u) << 16);
}

// async global->LDS, 16B per lane; LDS dst is wave-uniform base + 16*lane
__device__ __forceinline__ void gl2lds16(const u16* gsrc, u16* ldst) {
    __builtin_amdgcn_global_load_lds(
        (const __attribute__((address_space(1))) void*)gsrc,
        (__attribute__((address_space(3))) void*)ldst, 16, 0, 0);
}

// raw barrier / waitcnt (no compiler-attached vmcnt(0) drain)
#define RAW_BARRIER()   asm volatile("s_barrier" ::: "memory")
#define WAIT_VM(n)      asm volatile("s_waitcnt vmcnt(" #n ")" ::: "memory")

// ---------------- initial LayerNorm x -> bf16 g (once, pre-loop) -----------
__global__ __launch_bounds__(256) void ln_kernel(const float* __restrict__ x,
    const float* __restrict__ gamma, const float* __restrict__ beta,
    u16* __restrict__ g)
{
    int row = blockIdx.x;
    const float* xr = x + (size_t)row * 768;
    u16* gr = g + (size_t)row * 768;
    int t = threadIdx.x;
    float v0 = xr[t], v1 = xr[t + 256], v2 = xr[t + 512];
    float s = v0 + v1 + v2;
    #pragma unroll
    for (int off = 32; off > 0; off >>= 1) s += __shfl_down(s, off);
    __shared__ float red[8];
    int wid = t >> 6, lane = t & 63;
    if (lane == 0) red[wid] = s;
    __syncthreads();
    if (t == 0) red[0] = (red[0] + red[1] + red[2] + red[3]) * (1.0f / 768.0f);
    __syncthreads();
    float mu = red[0];
    float d0 = v0 - mu, d1 = v1 - mu, d2 = v2 - mu;
    float ss = d0*d0 + d1*d1 + d2*d2;
    #pragma unroll
    for (int off = 32; off > 0; off >>= 1) ss += __shfl_down(ss, off);
    if (lane == 0) red[4 + wid] = ss;
    __syncthreads();
    if (t == 0) red[4] = rsqrtf((red[4] + red[5] + red[6] + red[7]) * (1.0f / 768.0f) + EPS_);
    __syncthreads();
    float rs = red[4];
    gr[t]       = f2bf(gamma[t]       * d0 * rs + beta[t]);
    gr[t + 256] = f2bf(gamma[t + 256] * d1 * rs + beta[t + 256]);
    gr[t + 512] = f2bf(gamma[t + 512] * d2 * rs + beta[t + 512]);
}

// ------- fused: xc += alpha*(P0+P1); g = LN(xc)  (one block per row) --------
// part is bf16 now (halves the footprint + traffic of the partial buffers)
__global__ __launch_bounds__(192) void reduce_ln(const u16* __restrict__ part,
    float* __restrict__ xc, const float* __restrict__ gamma,
    const float* __restrict__ beta, u16* __restrict__ g)
{
    int row = blockIdx.x, t = threadIdx.x;
    const u16x4* p0 = (const u16x4*)(part + (size_t)row * 768);
    const u16x4* p1 = (const u16x4*)(part + (size_t)(8192 + row) * 768);
    f32x4* xr = (f32x4*)(xc + (size_t)row * 768);
    f32x4 v = xr[t];
    u16x4 a = p0[t], b = p1[t];
    #pragma unroll
    for (int e = 0; e < 4; ++e) v[e] = fmaf(ALPHA_, bf2f(a[e]) + bf2f(b[e]), v[e]);
    xr[t] = v;
    float s = (v[0] + v[1]) + (v[2] + v[3]);
    #pragma unroll
    for (int off = 32; off > 0; off >>= 1) s += __shfl_down(s, off);
    __shared__ float red[8];
    int wid = t >> 6, lane = t & 63;
    if (lane == 0) red[wid] = s;
    __syncthreads();
    if (t == 0) red[0] = (red[0] + red[1] + red[2]) * (1.0f / 768.0f);
    __syncthreads();
    float mu = red[0];
    f32x4 d;
    #pragma unroll
    for (int e = 0; e < 4; ++e) d[e] = v[e] - mu;
    float ss = (d[0]*d[0] + d[1]*d[1]) + (d[2]*d[2] + d[3]*d[3]);
    #pragma unroll
    for (int off = 32; off > 0; off >>= 1) ss += __shfl_down(ss, off);
    if (lane == 0) red[4 + wid] = ss;
    __syncthreads();
    if (t == 0) red[4] = rsqrtf((red[4] + red[5] + red[6]) * (1.0f / 768.0f) + EPS_);
    __syncthreads();
    float rs = red[4];
    const f32x4 gm = *(const f32x4*)&gamma[t * 4];
    const f32x4 bt = *(const f32x4*)&beta[t * 4];
    u16x4 o;
    #pragma unroll
    for (int e = 0; e < 4; ++e) o[e] = f2bf(fmaf(gm[e], d[e] * rs, bt[e]));
    *(u16x4*)&g[(size_t)row * 768 + t * 4] = o;
}

// ---------------- fp32 -> bf16 convert ----------------
__global__ __launch_bounds__(256) void convert_bf(const float* __restrict__ src,
                                                  u16* __restrict__ dst, int n4)
{
    int i = blockIdx.x * 256 + threadIdx.x;
    if (i < n4) {
        f32x4 v = *(const f32x4*)&src[i * 4];
        u16x4 o;
        #pragma unroll
        for (int e = 0; e < 4; ++e) o[e] = f2bf(v[e]);
        *(u16x4*)&dst[i * 4] = o;
    }
}

// -------- transpose-convert: Wcat [4608x768] f32 -> WcatT [768x4608] bf16 ----
__global__ __launch_bounds__(256) void transpose_bf(const float* __restrict__ Wq,
    const float* __restrict__ Wk, const float* __restrict__ xi, u16* __restrict__ out)
{
    __shared__ float tile[64][65];
    int rb = blockIdx.x * 64, cb = blockIdx.y * 64;
    const float* src;
    if (rb < 768) src = Wq + (size_t)rb * 768;
    else if (rb < 1536) src = Wk + (size_t)(rb - 768) * 768;
    else src = xi + (size_t)(rb - 1536) * 768;
    int t = threadIdx.x;
    #pragma unroll
    for (int it = 0; it < 4; ++it) {
        int r = (t >> 4) + 16 * it;
        f32x4 v = *(const f32x4*)&src[(size_t)r * 768 + cb + (t & 15) * 4];
        #pragma unroll
        for (int e = 0; e < 4; ++e) tile[r][(t & 15) * 4 + e] = v[e];
    }
    __syncthreads();
    #pragma unroll
    for (int it = 0; it < 4; ++it) {
        int cl = (t >> 4) + 16 * it;
        u16x4 o;
        #pragma unroll
        for (int e = 0; e < 4; ++e) o[e] = f2bf(tile[(t & 15) * 4 + e][cl]);
        *(u16x4*)&out[(size_t)(cb + cl) * 4608 + rb + (t & 15) * 4] = o;
    }
}

// ---------------- fused fwd GEMM: [qk | relu-mid] = g . Wcat^T --------------
// PERSISTENT: 768 blocks x 3 consecutive n-tiles each. m-slab fixed per block
// (A-tile L2-hot for tiles 2-3); next tile's first 2 stages issued before the
// epilogue so the prologue latency is hidden. 2-stage ping-pong, dual raw
// barriers, static addressing, XCD-swizzled.
__global__ __launch_bounds__(256, 4) void gemm_fwd(
    const u16* __restrict__ A,      // g [8192 x 768]
    const u16* __restrict__ Bt,     // Wcat rows [4608 x 768] (Wq|Wk|xi)
    u16* __restrict__ qkb, u16* __restrict__ qkT, u16* __restrict__ midb)
{
    __shared__ __align__(16) u16 As[2][4096];
    __shared__ __align__(16) u16 Bs[2][4096];
    const int t = threadIdx.x, w = t >> 6, l = t & 63, g = l >> 4, cid = l & 15;
    const int lr = l & 15, lc = l >> 4;
    const int flat = blockIdx.x;
    const int xcd = flat & 7, slot = flat >> 3;   // 96 slots per XCD
    const int mloc = slot % 8, ngrp = slot / 8;   // 8 m-tiles, 12 n-groups
    const int bm = (xcd * 8 + mloc) * 128;
    const int RO = (w >> 1) * 64, CO = (w & 1) * 64;

    const u16* gaB0 = A + (size_t)(bm + 32 * w + lr) * 768 + 8 * lc;
    const u16* gaB1 = A + (size_t)(bm + 32 * w + 16 + lr) * 768 + 8 * lc;
    const u16* gbB0 = Bt + (size_t)(32 * w + lr) * 768 + 8 * lc;
    const u16* gbB1 = Bt + (size_t)(32 * w + 16 + lr) * 768 + 8 * lc;

    const u16 *ga0, *ga1, *gb0, *gb1;
    auto setptr = [&](int bn) {
        ga0 = gaB0; ga1 = gaB1;
        gb0 = gbB0 + (size_t)bn * 768; gb1 = gbB1 + (size_t)bn * 768;
    };
    auto stage = [&](int buf, int off) {
        gl2lds16(ga0 + off, &As[buf][(64 * (2 * w + 0) + l) * 8]);
        gl2lds16(ga1 + off, &As[buf][(64 * (2 * w + 1) + l) * 8]);
        gl2lds16(gb0 + off, &Bs[buf][(64 * (2 * w + 0) + l) * 8]);
        gl2lds16(gb1 + off, &Bs[buf][(64 * (2 * w + 1) + l) * 8]);
    };
    auto adv = [&]() { ga0 += 64; ga1 += 64; gb0 += 64; gb1 += 64; };

    int bn = ngrp * 3 * 128;
    setptr(bn);
    stage(0, 0); stage(1, 32);

    #pragma unroll 1
    for (int it = 0; it < 3; ++it) {
        f32x4 acc[4][4] = {};
        auto compute = [&](int buf) {
            bf16x8 af[4], bfr[4];
            #pragma unroll
            for (int i = 0; i < 4; ++i) af[i]  = *(const bf16x8*)&As[buf][(64 * ((RO >> 4) + i) + l) * 8];
            #pragma unroll
            for (int j = 0; j < 4; ++j) bfr[j] = *(const bf16x8*)&Bs[buf][(64 * ((CO >> 4) + j) + l) * 8];
            #pragma unroll
            for (int i = 0; i < 4; ++i)
                #pragma unroll
                for (int j = 0; j < 4; ++j)
                    acc[i][j] = MFMA(af[i], bfr[j], acc[i][j], 0, 0, 0);
        };

        #pragma unroll 1
        for (int ii = 0; ii < 11; ++ii) {
            WAIT_VM(4); RAW_BARRIER(); compute(0); RAW_BARRIER(); stage(0, 64);
            WAIT_VM(4); RAW_BARRIER(); compute(1); RAW_BARRIER(); stage(1, 96);
            adv();
        }
        WAIT_VM(4); RAW_BARRIER(); compute(0);
        WAIT_VM(0); RAW_BARRIER(); compute(1);
        RAW_BARRIER();                     // all waves done with LDS this tile
        if (it < 2) {                      // prefetch next tile behind epilogue
            setptr(bn + 128);
            stage(0, 0); stage(1, 32);
        }

        if (bn < 1536) {
            int bidx = bm >> 10;
            #pragma unroll
            for (int i = 0; i < 4; ++i) {
                int tok = bm + RO + 16 * i + 4 * g;
                #pragma unroll
                for (int j = 0; j < 4; ++j) {
                    int col = bn + CO + 16 * j + cid;
                    int sel = col >= 768 ? 1 : 0;
                    int cc = col - 768 * sel;
                    int hh = cc >> 6, yy = cc & 63;
                    u16x4 tv;
                    #pragma unroll
                    for (int r = 0; r < 4; ++r) {
                        u16 bv = f2bf(acc[i][j][r]);
                        tv[r] = bv;
                        qkb[(size_t)(tok + r) * 1536 + col] = bv;
                    }
                    *(u16x4*)&qkT[((((size_t)bidx * 12 + hh) * 2 + sel) * 64 + yy) * 1024 + (tok & 1023)] = tv;
                }
            }
        } else {
            #pragma unroll
            for (int i = 0; i < 4; ++i)
                #pragma unroll
                for (int r = 0; r < 4; ++r) {
                    size_t row = bm + RO + 16 * i + 4 * g + r;
                    #pragma unroll
                    for (int j = 0; j < 4; ++j) {
                        int col = bn + CO + 16 * j + cid;
                        midb[row * 4608 + col] = f2bf(fmaxf(acc[i][j][r], 0.0f));
                    }
                }
        }
        bn += 128;
    }
}

// ------- update GEMM: part[z] = mid . WcatT (K-half z), bf16 partials -------
// 1-D grid 768, XCD-swizzled (z-outer / m-mid / n-inner per XCD).
__global__ __launch_bounds__(256, 4) void gemm_upd(
    const u16* __restrict__ A,      // mid [8192 x 4608]
    const u16* __restrict__ Bt,     // WcatT [768 x 4608]
    u16* __restrict__ part)         // [2][8192][768] bf16
{
    __shared__ __align__(16) u16 As[2][4096];
    __shared__ __align__(16) u16 Bs[2][4096];
    const int t = threadIdx.x, w = t >> 6, l = t & 63, g = l >> 4, cid = l & 15;
    const int lr = l & 15, lc = l >> 4;
    const int flat = blockIdx.x;
    const int xcd = flat & 7, slot = flat >> 3;        // 96 slots per XCD
    const int z = slot / 48, rem = slot % 48;
    const int mloc = rem / 6, n = rem % 6;
    const int bm = ((xcd << 3) + mloc) * 128, bn = n * 128;
    const int kbeg = z * 2304;
    const int RO = (w >> 1) * 64, CO = (w & 1) * 64;
    u16* out = part + (size_t)z * 8192 * 768;
    f32x4 acc[4][4] = {};

    const u16* ga0 = A  + (size_t)(bm + 32 * w + lr) * 4608 + kbeg + 8 * lc;
    const u16* ga1 = A  + (size_t)(bm + 32 * w + 16 + lr) * 4608 + kbeg + 8 * lc;
    const u16* gb0 = Bt + (size_t)(bn + 32 * w + lr) * 4608 + kbeg + 8 * lc;
    const u16* gb1 = Bt + (size_t)(bn + 32 * w + 16 + lr) * 4608 + kbeg + 8 * lc;

    auto stage = [&](int buf, int off) {
        gl2lds16(ga0 + off, &As[buf][(64 * (2 * w + 0) + l) * 8]);
        gl2lds16(ga1 + off, &As[buf][(64 * (2 * w + 1) + l) * 8]);
        gl2lds16(gb0 + off, &Bs[buf][(64 * (2 * w + 0) + l) * 8]);
        gl2lds16(gb1 + off, &Bs[buf][(64 * (2 * w + 1) + l) * 8]);
    };
    auto compute = [&](int buf) {
        bf16x8 af[4], bfr[4];
        #pragma unroll
        for (int i = 0; i < 4; ++i) af[i]  = *(const bf16x8*)&As[buf][(64 * ((RO >> 4) + i) + l) * 8];
        #pragma unroll
        for (int j = 0; j < 4; ++j) bfr[j] = *(const bf16x8*)&Bs[buf][(64 * ((CO >> 4) + j) + l) * 8];
        #pragma unroll
        for (int i = 0; i < 4; ++i)
            #pragma unroll
            for (int j = 0; j < 4; ++j)
                acc[i][j] = MFMA(af[i], bfr[j], acc[i][j], 0, 0, 0);
    };
    auto adv = [&]() { ga0 += 64; ga1 += 64; gb0 += 64; gb1 += 64; };

    stage(0, 0); stage(1, 32);
    #pragma unroll 1
    for (int ii = 0; ii < 35; ++ii) {
        WAIT_VM(4); RAW_BARRIER(); compute(0); RAW_BARRIER(); stage(0, 64);
        WAIT_VM(4); RAW_BARRIER(); compute(1); RAW_BARRIER(); stage(1, 96);
        adv();
    }
    WAIT_VM(4); RAW_BARRIER(); compute(0);
    WAIT_VM(0); RAW_BARRIER(); compute(1);

    #pragma unroll
    for (int i = 0; i < 4; ++i)
        #pragma unroll
        for (int r = 0; r < 4; ++r) {
            size_t row = bm + RO + 16 * i + 4 * g + r;
            #pragma unroll
            for (int j = 0; j < 4; ++j)
                out[row * 768 + bn + CO + 16 * j + cid] = f2bf(acc[i][j][r]);
        }
}

// ---------------- dq: flash pass over k, 128-q tile, computes L and Aq -------
// XCD-swizzled 1-D grid 768: all 8 q-tiles of one bh co-resident on one XCD.
__global__ __launch_bounds__(256) void dq_kernel(const u16* __restrict__ qk,
    const u16* __restrict__ qkT, float* __restrict__ L, u16* __restrict__ mid)
{
    const int flat = blockIdx.x;
    const int xcd = flat & 7, slot = flat >> 3;       // 96 slots per XCD
    const int bh = xcd * 12 + slot / 8;               // 12 bh per XCD
    const int q0 = (slot % 8) << 7;
    const int b = bh / H_, h = bh % H_;
    const u16* qbase = qk + (size_t)b * 1024 * 1536 + h * 64;
    const u16* kbase = qbase + 768;
    const u16* ktg = qkT + ((size_t)bh * 2 + 1) * 64 * 1024;   // K^T [y][1024]
    __shared__ __align__(16) u16 Qs[128 * 64], Kn[64 * 64], Kt[64 * 64], Ps[128 * 64];
    const int t = threadIdx.x, w = t >> 6, l = t & 63, g = l >> 4, cid = l & 15;
    const int lr = l & 15, lc = l >> 4;

    #pragma unroll
    for (int h2 = 0; h2 < 2; ++h2)
        #pragma unroll
        for (int ch = 0; ch < 2; ++ch)
            gl2lds16(&qbase[(size_t)(q0 + 32 * w + 16 * h2 + lr) * 1536 + 32 * ch + 8 * lc],
                     &Qs[(128 * (2 * w + h2) + 64 * ch + l) * 8]);
    __syncthreads();
    bf16x8 QF[2][2];
    #pragma unroll
    for (int jj = 0; jj < 2; ++jj)
        #pragma unroll
        for (int hh = 0; hh < 2; ++hh)
            QF[jj][hh] = *(const bf16x8*)&Qs[(128 * (2 * w + jj) + 64 * hh + l) * 8];

    f32x4 acc[2][4] = {};
    float lrun[2] = {0.0f, 0.0f};

    for (int kt = 0; kt < 16; ++kt) {
        __syncthreads();
        #pragma unroll
        for (int ch = 0; ch < 2; ++ch) {
            gl2lds16(&kbase[(size_t)(kt * 64 + 16 * w + lr) * 1536 + 32 * ch + 8 * lc],
                     &Kn[(128 * w + 64 * ch + l) * 8]);
            gl2lds16(&ktg[(size_t)(16 * w + lr) * 1024 + kt * 64 + 32 * ch + 8 * lc],
                     &Kt[(128 * w + 64 * ch + l) * 8]);
        }
        __syncthreads();
        f32x4 s[4][2];
        #pragma unroll
        for (int i = 0; i < 4; ++i) {
            bf16x8 a0 = *(const bf16x8*)&Kn[(128 * i + l) * 8];
            bf16x8 a1 = *(const bf16x8*)&Kn[(128 * i + 64 + l) * 8];
            #pragma unroll
            for (int jj = 0; jj < 2; ++jj) {
                f32x4 z = {0.f, 0.f, 0.f, 0.f};
                z = MFMA(a0, QF[jj][0], z, 0, 0, 0);
                z = MFMA(a1, QF[jj][1], z, 0, 0, 0);
                s[i][jj] = z;
            }
        }
        #pragma unroll
        for (int jj = 0; jj < 2; ++jj) {
            float psum = 0.0f;
            #pragma unroll
            for (int i = 0; i < 4; ++i) {
                u16x4 pv;
                #pragma unroll
                for (int r = 0; r < 4; ++r) {
                    float p = __expf(s[i][jj][r] * BETA_);
                    psum += p;
                    pv[r] = f2bf(p);
                }
                *(u16x4*)&Ps[(128 * (2 * w + jj) + 32 * i + 16 * (g >> 1) + cid) * 8 + 4 * (g & 1)] = pv;
            }
            psum += __shfl_xor(psum, 16);
            psum += __shfl_xor(psum, 32);
            lrun[jj] += psum;
        }
        #pragma unroll
        for (int jj = 0; jj < 2; ++jj) {
            bf16x8 p0 = *(const bf16x8*)&Ps[(128 * (2 * w + jj) + l) * 8];
            bf16x8 p1 = *(const bf16x8*)&Ps[(128 * (2 * w + jj) + 64 + l) * 8];
            #pragma unroll
            for (int j = 0; j < 4; ++j) {
                acc[jj][j] = MFMA(p0, *(const bf16x8*)&Kt[(128 * j + l) * 8], acc[jj][j], 0, 0, 0);
                acc[jj][j] = MFMA(p1, *(const bf16x8*)&Kt[(128 * j + 64 + l) * 8], acc[jj][j], 0, 0, 0);
            }
        }
    }
    #pragma unroll
    for (int jj = 0; jj < 2; ++jj) {
        if (g == 0)
            L[(size_t)bh * 1024 + q0 + 32 * w + 16 * jj + cid] = __logf(lrun[jj]);
        float linv = 1.0f / lrun[jj];
        #pragma unroll
        for (int r = 0; r < 4; ++r) {
            float fr = __shfl(linv, 4 * g + r);
            int row = q0 + 32 * w + 16 * jj + 4 * g + r;
            #pragma unroll
            for (int j = 0; j < 4; ++j)
                mid[(size_t)(b * 1024 + row) * 4608 + h * 64 + 16 * j + cid] = f2bf(acc[jj][j][r] * fr);
        }
    }
}

// ---------------- dk: Ak[k] = sum_q exp(beta*S - L[q]) q, 128-k tile --------
__global__ __launch_bounds__(256) void dk_kernel(const u16* __restrict__ qk,
    const u16* __restrict__ qkT, const float* __restrict__ L, u16* __restrict__ mid)
{
    const int flat = blockIdx.x;
    const int xcd = flat & 7, slot = flat >> 3;
    const int bh = xcd * 12 + slot / 8;
    const int k0 = (slot % 8) << 7;
    const int b = bh / H_, h = bh % H_;
    const u16* qbase = qk + (size_t)b * 1024 * 1536 + h * 64;
    const u16* kbase = qbase + 768;
    const u16* qtg = qkT + ((size_t)bh * 2 + 0) * 64 * 1024;   // Q^T [y][1024]
    __shared__ __align__(16) u16 Kr[128 * 64], Qn[64 * 64], Qt[64 * 64], Ps[128 * 64];
    __shared__ __align__(16) float Ls[64];
    const int t = threadIdx.x, w = t >> 6, l = t & 63, g = l >> 4, cid = l & 15;
    const int lr = l & 15, lc = l >> 4;

    #pragma unroll
    for (int h2 = 0; h2 < 2; ++h2)
        #pragma unroll
        for (int ch = 0; ch < 2; ++ch)
            gl2lds16(&kbase[(size_t)(k0 + 32 * w + 16 * h2 + lr) * 1536 + 32 * ch + 8 * lc],
                     &Kr[(128 * (2 * w + h2) + 64 * ch + l) * 8]);
    __syncthreads();
    bf16x8 KF[2][2];
    #pragma unroll
    for (int jj = 0; jj < 2; ++jj)
        #pragma unroll
        for (int hh = 0; hh < 2; ++hh)
            KF[jj][hh] = *(const bf16x8*)&Kr[(128 * (2 * w + jj) + 64 * hh + l) * 8];

    f32x4 acc[2][4] = {};
    for (int qt = 0; qt < 16; ++qt) {
        __syncthreads();
        #pragma unroll
        for (int ch = 0; ch < 2; ++ch) {
            gl2lds16(&qbase[(size_t)(qt * 64 + 16 * w + lr) * 1536 + 32 * ch + 8 * lc],
                     &Qn[(128 * w + 64 * ch + l) * 8]);
            gl2lds16(&qtg[(size_t)(16 * w + lr) * 1024 + qt * 64 + 32 * ch + 8 * lc],
                     &Qt[(128 * w + 64 * ch + l) * 8]);
        }
        if (t < 64) Ls[t] = L[(size_t)bh * 1024 + qt * 64 + t];
        __syncthreads();
        #pragma unroll
        for (int i = 0; i < 4; ++i) {
            bf16x8 a0 = *(const bf16x8*)&Qn[(128 * i + l) * 8];
            bf16x8 a1 = *(const bf16x8*)&Qn[(128 * i + 64 + l) * 8];
            f32x4 lv = *(const f32x4*)&Ls[16 * i + 4 * g];
            #pragma unroll
            for (int jj = 0; jj < 2; ++jj) {
                f32x4 z = {0.f, 0.f, 0.f, 0.f};
                z = MFMA(a0, KF[jj][0], z, 0, 0, 0);
                z = MFMA(a1, KF[jj][1], z, 0, 0, 0);
                u16x4 pv;
                #pragma unroll
                for (int r = 0; r < 4; ++r)
                    pv[r] = f2bf(__expf(fmaf(z[r], BETA_, -lv[r])));
                *(u16x4*)&Ps[(128 * (2 * w + jj) + 32 * i + 16 * (g >> 1) + cid) * 8 + 4 * (g & 1)] = pv;
            }
        }
        #pragma unroll
        for (int jj = 0; jj < 2; ++jj) {
            bf16x8 p0 = *(const bf16x8*)&Ps[(128 * (2 * w + jj) + l) * 8];
            bf16x8 p1 = *(const bf16x8*)&Ps[(128 * (2 * w + jj) + 64 + l) * 8];
            #pragma unroll
            for (int j = 0; j < 4; ++j) {
                acc[jj][j] = MFMA(p0, *(const bf16x8*)&Qt[(128 * j + l) * 8], acc[jj][j], 0, 0, 0);
                acc[jj][j] = MFMA(p1, *(const bf16x8*)&Qt[(128 * j + 64 + l) * 8], acc[jj][j], 0, 0, 0);
            }
        }
    }
    #pragma unroll
    for (int jj = 0; jj < 2; ++jj)
        #pragma unroll
        for (int r = 0; r < 4; ++r) {
            int row = k0 + 32 * w + 16 * jj + 4 * g + r;
            #pragma unroll
            for (int j = 0; j < 4; ++j)
                mid[(size_t)(b * 1024 + row) * 4608 + 768 + h * 64 + 16 * j + cid] = f2bf(acc[jj][j][r]);
        }
}

// ---------------------------------------------------------------------------
extern "C" void kernel_launch(void* const* d_in, const int* in_sizes, int n_in,
                              void* d_out, int out_size, void* d_ws, size_t ws_size,
                              hipStream_t stream)
{
    const float* x     = (const float*)d_in[0];
    const float* gamma = (const float*)d_in[1];
    const float* betap = (const float*)d_in[2];
    const float* Wq    = (const float*)d_in[3];
    const float* Wk    = (const float*)d_in[4];
    const float* xi    = (const float*)d_in[5];
    float* xc = (float*)d_out;

    char* p = (char*)d_ws;
    u16* wcat_bf  = (u16*)p; p += (size_t)4608 * 768 * 2;   // [Wq;Wk;xi] rows
    u16* wcatT_bf = (u16*)p; p += (size_t)768 * 4608 * 2;
    u16* g_bf     = (u16*)p; p += (size_t)NTOK * 768 * 2;
    u16* qk_bf    = (u16*)p; p += (size_t)NTOK * 1536 * 2;
    u16* qkT_bf   = (u16*)p; p += (size_t)96 * 2 * 64 * 1024 * 2;
    u16* mid_bf   = (u16*)p; p += (size_t)NTOK * 4608 * 2;
    u16* part     = (u16*)p; p += (size_t)2 * NTOK * 768 * 2;   // bf16 partials
    float* L      = (float*)p; p += (size_t)96 * 1024 * 4;
    (void)ws_size; (void)in_sizes; (void)n_in; (void)out_size;

    hipMemcpyAsync(xc, x, (size_t)NTOK * 768 * 4, hipMemcpyDeviceToDevice, stream);

    convert_bf<<<576, 256, 0, stream>>>(Wq, wcat_bf, 147456);
    convert_bf<<<576, 256, 0, stream>>>(Wk, wcat_bf + 768 * 768, 147456);
    convert_bf<<<2304, 256, 0, stream>>>(xi, wcat_bf + 2 * 768 * 768, 589824);
    transpose_bf<<<dim3(72, 12), 256, 0, stream>>>(Wq, Wk, xi, wcatT_bf);

    // g_0 = LN(x)
    ln_kernel<<<NTOK, 256, 0, stream>>>(x, gamma, betap, g_bf);

    for (int step = 0; step < STEPS_; ++step) {
        // fused: qk (+qkT) and relu-mid, persistent 3-tile blocks
        gemm_fwd<<<768, 256, 0, stream>>>(
            g_bf, wcat_bf, qk_bf, qkT_bf, mid_bf);
        // Aq (+L), Ak  (XCD-swizzled)
        dq_kernel<<<768, 256, 0, stream>>>(qk_bf, qkT_bf, L, mid_bf);
        dk_kernel<<<768, 256, 0, stream>>>(qk_bf, qkT_bf, L, mid_bf);
        // part[z] = mid . Wcat (K halves, bf16 partials, XCD-swizzled)
        gemm_upd<<<768, 256, 0, stream>>>(mid_bf, wcatT_bf, part);
        // xc += alpha*(P0+P1); g = LN(xc)   (fused)
        reduce_ln<<<NTOK, 192, 0, stream>>>(part, xc, gamma, betap, g_bf);
    }
}

// Round 11
// 3927.378 us; speedup vs baseline: 1.0591x; 1.0591x over previous
//
#include <hip/hip_runtime.h>
#include <math.h>

#define H_ 12
#define STEPS_ 12
#define ALPHA_ 0.1f
#define EPS_ 1e-5f
#define BETA_ 0.125f          // 1/sqrt(64)
#define NTOK 8192

typedef unsigned short u16;
typedef __attribute__((ext_vector_type(8))) u16 u16x8;
typedef __attribute__((ext_vector_type(4))) u16 u16x4;
typedef __attribute__((ext_vector_type(4))) float f32x4;
typedef __attribute__((ext_vector_type(8))) __bf16 bf16x8;

#define MFMA __builtin_amdgcn_mfma_f32_16x16x32_bf16

__device__ __forceinline__ u16 f2bf(float x) {
    unsigned u = __float_as_uint(x);
    u += 0x7FFFu + ((u >> 16) & 1u);
    return (u16)(u >> 16);
}
__device__ __forceinline__ float bf2f(u16 u) {
    return __uint_as_float(((unsigned)u) << 16);
}

// async global->LDS, 16B per lane; LDS dst is wave-uniform base + 16*lane
__device__ __forceinline__ void gl2lds16(const u16* gsrc, u16* ldst) {
    __builtin_amdgcn_global_load_lds(
        (const __attribute__((address_space(1))) void*)gsrc,
        (__attribute__((address_space(3))) void*)ldst, 16, 0, 0);
}

// raw barrier / waitcnt (no compiler-attached vmcnt(0) drain)
#define RAW_BARRIER()   asm volatile("s_barrier" ::: "memory")
#define WAIT_VM(n)      asm volatile("s_waitcnt vmcnt(" #n ")" ::: "memory")

// ---------------- initial LayerNorm x -> bf16 g (once, pre-loop) -----------
__global__ __launch_bounds__(256) void ln_kernel(const float* __restrict__ x,
    const float* __restrict__ gamma, const float* __restrict__ beta,
    u16* __restrict__ g)
{
    int row = blockIdx.x;
    const float* xr = x + (size_t)row * 768;
    u16* gr = g + (size_t)row * 768;
    int t = threadIdx.x;
    float v0 = xr[t], v1 = xr[t + 256], v2 = xr[t + 512];
    float s = v0 + v1 + v2;
    #pragma unroll
    for (int off = 32; off > 0; off >>= 1) s += __shfl_down(s, off);
    __shared__ float red[8];
    int wid = t >> 6, lane = t & 63;
    if (lane == 0) red[wid] = s;
    __syncthreads();
    if (t == 0) red[0] = (red[0] + red[1] + red[2] + red[3]) * (1.0f / 768.0f);
    __syncthreads();
    float mu = red[0];
    float d0 = v0 - mu, d1 = v1 - mu, d2 = v2 - mu;
    float ss = d0*d0 + d1*d1 + d2*d2;
    #pragma unroll
    for (int off = 32; off > 0; off >>= 1) ss += __shfl_down(ss, off);
    if (lane == 0) red[4 + wid] = ss;
    __syncthreads();
    if (t == 0) red[4] = rsqrtf((red[4] + red[5] + red[6] + red[7]) * (1.0f / 768.0f) + EPS_);
    __syncthreads();
    float rs = red[4];
    gr[t]       = f2bf(gamma[t]       * d0 * rs + beta[t]);
    gr[t + 256] = f2bf(gamma[t + 256] * d1 * rs + beta[t + 256]);
    gr[t + 512] = f2bf(gamma[t + 512] * d2 * rs + beta[t + 512]);
}

// ------- fused: xc += alpha*(P0+P1); g = LN(xc)  (one block per row) --------
__global__ __launch_bounds__(192) void reduce_ln(const u16* __restrict__ part,
    float* __restrict__ xc, const float* __restrict__ gamma,
    const float* __restrict__ beta, u16* __restrict__ g)
{
    int row = blockIdx.x, t = threadIdx.x;
    const u16x4* p0 = (const u16x4*)(part + (size_t)row * 768);
    const u16x4* p1 = (const u16x4*)(part + (size_t)(8192 + row) * 768);
    f32x4* xr = (f32x4*)(xc + (size_t)row * 768);
    f32x4 v = xr[t];
    u16x4 a = p0[t], b = p1[t];
    #pragma unroll
    for (int e = 0; e < 4; ++e) v[e] = fmaf(ALPHA_, bf2f(a[e]) + bf2f(b[e]), v[e]);
    xr[t] = v;
    float s = (v[0] + v[1]) + (v[2] + v[3]);
    #pragma unroll
    for (int off = 32; off > 0; off >>= 1) s += __shfl_down(s, off);
    __shared__ float red[8];
    int wid = t >> 6, lane = t & 63;
    if (lane == 0) red[wid] = s;
    __syncthreads();
    if (t == 0) red[0] = (red[0] + red[1] + red[2]) * (1.0f / 768.0f);
    __syncthreads();
    float mu = red[0];
    f32x4 d;
    #pragma unroll
    for (int e = 0; e < 4; ++e) d[e] = v[e] - mu;
    float ss = (d[0]*d[0] + d[1]*d[1]) + (d[2]*d[2] + d[3]*d[3]);
    #pragma unroll
    for (int off = 32; off > 0; off >>= 1) ss += __shfl_down(ss, off);
    if (lane == 0) red[4 + wid] = ss;
    __syncthreads();
    if (t == 0) red[4] = rsqrtf((red[4] + red[5] + red[6]) * (1.0f / 768.0f) + EPS_);
    __syncthreads();
    float rs = red[4];
    const f32x4 gm = *(const f32x4*)&gamma[t * 4];
    const f32x4 bt = *(const f32x4*)&beta[t * 4];
    u16x4 o;
    #pragma unroll
    for (int e = 0; e < 4; ++e) o[e] = f2bf(fmaf(gm[e], d[e] * rs, bt[e]));
    *(u16x4*)&g[(size_t)row * 768 + t * 4] = o;
}

// ---------------- fp32 -> bf16 convert ----------------
__global__ __launch_bounds__(256) void convert_bf(const float* __restrict__ src,
                                                  u16* __restrict__ dst, int n4)
{
    int i = blockIdx.x * 256 + threadIdx.x;
    if (i < n4) {
        f32x4 v = *(const f32x4*)&src[i * 4];
        u16x4 o;
        #pragma unroll
        for (int e = 0; e < 4; ++e) o[e] = f2bf(v[e]);
        *(u16x4*)&dst[i * 4] = o;
    }
}

// -------- transpose-convert: Wcat [4608x768] f32 -> WcatT [768x4608] bf16 ----
__global__ __launch_bounds__(256) void transpose_bf(const float* __restrict__ Wq,
    const float* __restrict__ Wk, const float* __restrict__ xi, u16* __restrict__ out)
{
    __shared__ float tile[64][65];
    int rb = blockIdx.x * 64, cb = blockIdx.y * 64;
    const float* src;
    if (rb < 768) src = Wq + (size_t)rb * 768;
    else if (rb < 1536) src = Wk + (size_t)(rb - 768) * 768;
    else src = xi + (size_t)(rb - 1536) * 768;
    int t = threadIdx.x;
    #pragma unroll
    for (int it = 0; it < 4; ++it) {
        int r = (t >> 4) + 16 * it;
        f32x4 v = *(const f32x4*)&src[(size_t)r * 768 + cb + (t & 15) * 4];
        #pragma unroll
        for (int e = 0; e < 4; ++e) tile[r][(t & 15) * 4 + e] = v[e];
    }
    __syncthreads();
    #pragma unroll
    for (int it = 0; it < 4; ++it) {
        int cl = (t >> 4) + 16 * it;
        u16x4 o;
        #pragma unroll
        for (int e = 0; e < 4; ++e) o[e] = f2bf(tile[(t & 15) * 4 + e][cl]);
        *(u16x4*)&out[(size_t)(cb + cl) * 4608 + rb + (t & 15) * 4] = o;
    }
}

// ---------------- fused fwd GEMM: [qk | relu-mid] = g . Wcat^T --------------
// R9 version (proven 124 us): 128x128 tile, BK=32, 2-stage ping-pong + dual
// raw barriers, static addressing, XCD-swizzled 1-D grid 2304.
__global__ __launch_bounds__(256, 4) void gemm_fwd(
    const u16* __restrict__ A,      // g [8192 x 768]
    const u16* __restrict__ Bt,     // Wcat rows [4608 x 768] (Wq|Wk|xi)
    u16* __restrict__ qkb, u16* __restrict__ qkT, u16* __restrict__ midb)
{
    __shared__ __align__(16) u16 As[2][4096];
    __shared__ __align__(16) u16 Bs[2][4096];
    const int t = threadIdx.x, w = t >> 6, l = t & 63, g = l >> 4, cid = l & 15;
    const int lr = l & 15, lc = l >> 4;
    const int flat = blockIdx.x;
    const int xcd = flat & 7, slot = flat >> 3;   // 288 slots per XCD
    const int nid = slot / 8, mloc = slot % 8;    // n-outer, m-inner
    const int bm = (xcd * 8 + mloc) * 128;
    const int bn = nid * 128;
    const int RO = (w >> 1) * 64, CO = (w & 1) * 64;
    f32x4 acc[4][4] = {};

    const u16* ga0 = A  + (size_t)(bm + 32 * w + lr) * 768 + 8 * lc;
    const u16* ga1 = A  + (size_t)(bm + 32 * w + 16 + lr) * 768 + 8 * lc;
    const u16* gb0 = Bt + (size_t)(bn + 32 * w + lr) * 768 + 8 * lc;
    const u16* gb1 = Bt + (size_t)(bn + 32 * w + 16 + lr) * 768 + 8 * lc;

    auto stage = [&](int buf, int off) {
        gl2lds16(ga0 + off, &As[buf][(64 * (2 * w + 0) + l) * 8]);
        gl2lds16(ga1 + off, &As[buf][(64 * (2 * w + 1) + l) * 8]);
        gl2lds16(gb0 + off, &Bs[buf][(64 * (2 * w + 0) + l) * 8]);
        gl2lds16(gb1 + off, &Bs[buf][(64 * (2 * w + 1) + l) * 8]);
    };
    auto compute = [&](int buf) {
        bf16x8 af[4], bfr[4];
        #pragma unroll
        for (int i = 0; i < 4; ++i) af[i]  = *(const bf16x8*)&As[buf][(64 * ((RO >> 4) + i) + l) * 8];
        #pragma unroll
        for (int j = 0; j < 4; ++j) bfr[j] = *(const bf16x8*)&Bs[buf][(64 * ((CO >> 4) + j) + l) * 8];
        #pragma unroll
        for (int i = 0; i < 4; ++i)
            #pragma unroll
            for (int j = 0; j < 4; ++j)
                acc[i][j] = MFMA(af[i], bfr[j], acc[i][j], 0, 0, 0);
    };
    auto adv = [&]() { ga0 += 64; ga1 += 64; gb0 += 64; gb1 += 64; };

    stage(0, 0); stage(1, 32);
    #pragma unroll 1
    for (int ii = 0; ii < 11; ++ii) {
        WAIT_VM(4); RAW_BARRIER(); compute(0); RAW_BARRIER(); stage(0, 64);
        WAIT_VM(4); RAW_BARRIER(); compute(1); RAW_BARRIER(); stage(1, 96);
        adv();
    }
    WAIT_VM(4); RAW_BARRIER(); compute(0);
    WAIT_VM(0); RAW_BARRIER(); compute(1);

    if (bn < 1536) {
        int bidx = bm >> 10;
        #pragma unroll
        for (int i = 0; i < 4; ++i) {
            int tok = bm + RO + 16 * i + 4 * g;
            #pragma unroll
            for (int j = 0; j < 4; ++j) {
                int col = bn + CO + 16 * j + cid;
                int sel = col >= 768 ? 1 : 0;
                int cc = col - 768 * sel;
                int hh = cc >> 6, yy = cc & 63;
                u16x4 tv;
                #pragma unroll
                for (int r = 0; r < 4; ++r) {
                    u16 bv = f2bf(acc[i][j][r]);
                    tv[r] = bv;
                    qkb[(size_t)(tok + r) * 1536 + col] = bv;
                }
                *(u16x4*)&qkT[((((size_t)bidx * 12 + hh) * 2 + sel) * 64 + yy) * 1024 + (tok & 1023)] = tv;
            }
        }
    } else {
        #pragma unroll
        for (int i = 0; i < 4; ++i)
            #pragma unroll
            for (int r = 0; r < 4; ++r) {
                size_t row = bm + RO + 16 * i + 4 * g + r;
                #pragma unroll
                for (int j = 0; j < 4; ++j) {
                    int col = bn + CO + 16 * j + cid;
                    midb[row * 4608 + col] = f2bf(fmaxf(acc[i][j][r], 0.0f));
                }
            }
    }
}

// ------- update GEMM: part[z] = mid . WcatT (K-half z), bf16 partials -------
__global__ __launch_bounds__(256, 4) void gemm_upd(
    const u16* __restrict__ A,      // mid [8192 x 4608]
    const u16* __restrict__ Bt,     // WcatT [768 x 4608]
    u16* __restrict__ part)         // [2][8192][768] bf16
{
    __shared__ __align__(16) u16 As[2][4096];
    __shared__ __align__(16) u16 Bs[2][4096];
    const int t = threadIdx.x, w = t >> 6, l = t & 63, g = l >> 4, cid = l & 15;
    const int lr = l & 15, lc = l >> 4;
    const int flat = blockIdx.x;
    const int xcd = flat & 7, slot = flat >> 3;        // 96 slots per XCD
    const int z = slot / 48, rem = slot % 48;
    const int mloc = rem / 6, n = rem % 6;
    const int bm = ((xcd << 3) + mloc) * 128, bn = n * 128;
    const int kbeg = z * 2304;
    const int RO = (w >> 1) * 64, CO = (w & 1) * 64;
    u16* out = part + (size_t)z * 8192 * 768;
    f32x4 acc[4][4] = {};

    const u16* ga0 = A  + (size_t)(bm + 32 * w + lr) * 4608 + kbeg + 8 * lc;
    const u16* ga1 = A  + (size_t)(bm + 32 * w + 16 + lr) * 4608 + kbeg + 8 * lc;
    const u16* gb0 = Bt + (size_t)(bn + 32 * w + lr) * 4608 + kbeg + 8 * lc;
    const u16* gb1 = Bt + (size_t)(bn + 32 * w + 16 + lr) * 4608 + kbeg + 8 * lc;

    auto stage = [&](int buf, int off) {
        gl2lds16(ga0 + off, &As[buf][(64 * (2 * w + 0) + l) * 8]);
        gl2lds16(ga1 + off, &As[buf][(64 * (2 * w + 1) + l) * 8]);
        gl2lds16(gb0 + off, &Bs[buf][(64 * (2 * w + 0) + l) * 8]);
        gl2lds16(gb1 + off, &Bs[buf][(64 * (2 * w + 1) + l) * 8]);
    };
    auto compute = [&](int buf) {
        bf16x8 af[4], bfr[4];
        #pragma unroll
        for (int i = 0; i < 4; ++i) af[i]  = *(const bf16x8*)&As[buf][(64 * ((RO >> 4) + i) + l) * 8];
        #pragma unroll
        for (int j = 0; j < 4; ++j) bfr[j] = *(const bf16x8*)&Bs[buf][(64 * ((CO >> 4) + j) + l) * 8];
        #pragma unroll
        for (int i = 0; i < 4; ++i)
            #pragma unroll
            for (int j = 0; j < 4; ++j)
                acc[i][j] = MFMA(af[i], bfr[j], acc[i][j], 0, 0, 0);
    };
    auto adv = [&]() { ga0 += 64; ga1 += 64; gb0 += 64; gb1 += 64; };

    stage(0, 0); stage(1, 32);
    #pragma unroll 1
    for (int ii = 0; ii < 35; ++ii) {
        WAIT_VM(4); RAW_BARRIER(); compute(0); RAW_BARRIER(); stage(0, 64);
        WAIT_VM(4); RAW_BARRIER(); compute(1); RAW_BARRIER(); stage(1, 96);
        adv();
    }
    WAIT_VM(4); RAW_BARRIER(); compute(0);
    WAIT_VM(0); RAW_BARRIER(); compute(1);

    #pragma unroll
    for (int i = 0; i < 4; ++i)
        #pragma unroll
        for (int r = 0; r < 4; ++r) {
            size_t row = bm + RO + 16 * i + 4 * g + r;
            #pragma unroll
            for (int j = 0; j < 4; ++j)
                out[row * 768 + bn + CO + 16 * j + cid] = f2bf(acc[i][j][r]);
        }
}

// ---------------- dq: flash pass over k, 128-q tile, computes L and Aq -------
// Ping-pong staging: after QF is hoisted to registers, the Q slab (KB[0]) is
// dead -> reuse as 2nd K/Kt buffer. 48 KB total, 3 blocks/CU, vmcnt(4) pipeline.
__global__ __launch_bounds__(256) void dq_kernel(const u16* __restrict__ qk,
    const u16* __restrict__ qkT, float* __restrict__ L, u16* __restrict__ mid)
{
    const int flat = blockIdx.x;
    const int xcd = flat & 7, slot = flat >> 3;       // 96 slots per XCD
    const int bh = xcd * 12 + slot / 8;               // 12 bh per XCD
    const int q0 = (slot % 8) << 7;
    const int b = bh / H_, h = bh % H_;
    const u16* qbase = qk + (size_t)b * 1024 * 1536 + h * 64;
    const u16* kbase = qbase + 768;
    const u16* ktg = qkT + ((size_t)bh * 2 + 1) * 64 * 1024;   // K^T [y][1024]
    __shared__ __align__(16) u16 KB[2][8192];   // per buf: Kn [0,4096) | Kt [4096,8192)
    __shared__ __align__(16) u16 Ps[8192];
    const int t = threadIdx.x, w = t >> 6, l = t & 63, g = l >> 4, cid = l & 15;
    const int lr = l & 15, lc = l >> 4;

    // stage Q tile into KB[0] (16 KB), hoist fragments, then slab is dead
    #pragma unroll
    for (int h2 = 0; h2 < 2; ++h2)
        #pragma unroll
        for (int ch = 0; ch < 2; ++ch)
            gl2lds16(&qbase[(size_t)(q0 + 32 * w + 16 * h2 + lr) * 1536 + 32 * ch + 8 * lc],
                     &KB[0][(128 * (2 * w + h2) + 64 * ch + l) * 8]);
    __syncthreads();
    bf16x8 QF[2][2];
    #pragma unroll
    for (int jj = 0; jj < 2; ++jj)
        #pragma unroll
        for (int hh = 0; hh < 2; ++hh)
            QF[jj][hh] = *(const bf16x8*)&KB[0][(128 * (2 * w + jj) + 64 * hh + l) * 8];
    __syncthreads();   // all QF reads done before KB[0] is restaged

    auto stageK = [&](int buf, int kt) {   // 4 gl2lds per wave
        #pragma unroll
        for (int ch = 0; ch < 2; ++ch) {
            gl2lds16(&kbase[(size_t)(kt * 64 + 16 * w + lr) * 1536 + 32 * ch + 8 * lc],
                     &KB[buf][(128 * w + 64 * ch + l) * 8]);
            gl2lds16(&ktg[(size_t)(16 * w + lr) * 1024 + kt * 64 + 32 * ch + 8 * lc],
                     &KB[buf][4096 + (128 * w + 64 * ch + l) * 8]);
        }
    };

    f32x4 acc[2][4] = {};
    float lrun[2] = {0.0f, 0.0f};

    stageK(0, 0); stageK(1, 1);
    #pragma unroll 1
    for (int kt = 0; kt < 16; ++kt) {
        if (kt == 15) { WAIT_VM(0); } else { WAIT_VM(4); }
        RAW_BARRIER();
        const int buf = kt & 1;
        const u16* Kn = &KB[buf][0];
        const u16* Kt = &KB[buf][4096];
        f32x4 s[4][2];
        #pragma unroll
        for (int i = 0; i < 4; ++i) {
            bf16x8 a0 = *(const bf16x8*)&Kn[(128 * i + l) * 8];
            bf16x8 a1 = *(const bf16x8*)&Kn[(128 * i + 64 + l) * 8];
            #pragma unroll
            for (int jj = 0; jj < 2; ++jj) {
                f32x4 z = {0.f, 0.f, 0.f, 0.f};
                z = MFMA(a0, QF[jj][0], z, 0, 0, 0);
                z = MFMA(a1, QF[jj][1], z, 0, 0, 0);
                s[i][jj] = z;
            }
        }
        #pragma unroll
        for (int jj = 0; jj < 2; ++jj) {
            float psum = 0.0f;
            #pragma unroll
            for (int i = 0; i < 4; ++i) {
                u16x4 pv;
                #pragma unroll
                for (int r = 0; r < 4; ++r) {
                    float p = __expf(s[i][jj][r] * BETA_);
                    psum += p;
                    pv[r] = f2bf(p);
                }
                *(u16x4*)&Ps[(128 * (2 * w + jj) + 32 * i + 16 * (g >> 1) + cid) * 8 + 4 * (g & 1)] = pv;
            }
            psum += __shfl_xor(psum, 16);
            psum += __shfl_xor(psum, 32);
            lrun[jj] += psum;
        }
        #pragma unroll
        for (int jj = 0; jj < 2; ++jj) {
            bf16x8 p0 = *(const bf16x8*)&Ps[(128 * (2 * w + jj) + l) * 8];
            bf16x8 p1 = *(const bf16x8*)&Ps[(128 * (2 * w + jj) + 64 + l) * 8];
            #pragma unroll
            for (int j = 0; j < 4; ++j) {
                acc[jj][j] = MFMA(p0, *(const bf16x8*)&Kt[(128 * j + l) * 8], acc[jj][j], 0, 0, 0);
                acc[jj][j] = MFMA(p1, *(const bf16x8*)&Kt[(128 * j + 64 + l) * 8], acc[jj][j], 0, 0, 0);
            }
        }
        RAW_BARRIER();
        if (kt + 2 < 16) stageK(buf, kt + 2);
    }
    #pragma unroll
    for (int jj = 0; jj < 2; ++jj) {
        if (g == 0)
            L[(size_t)bh * 1024 + q0 + 32 * w + 16 * jj + cid] = __logf(lrun[jj]);
        float linv = 1.0f / lrun[jj];
        #pragma unroll
        for (int r = 0; r < 4; ++r) {
            float fr = __shfl(linv, 4 * g + r);
            int row = q0 + 32 * w + 16 * jj + 4 * g + r;
            #pragma unroll
            for (int j = 0; j < 4; ++j)
                mid[(size_t)(b * 1024 + row) * 4608 + h * 64 + 16 * j + cid] = f2bf(acc[jj][j][r] * fr);
        }
    }
}

// ---------------- dk: Ak[k] = sum_q exp(beta*S - L[q]) q, 128-k tile --------
// Same ping-pong aliasing (K slab dead after KF hoist). L read directly per
// lane (f32x4, L2-hot) instead of an LDS broadcast (racy under raw barriers).
__global__ __launch_bounds__(256) void dk_kernel(const u16* __restrict__ qk,
    const u16* __restrict__ qkT, const float* __restrict__ L, u16* __restrict__ mid)
{
    const int flat = blockIdx.x;
    const int xcd = flat & 7, slot = flat >> 3;
    const int bh = xcd * 12 + slot / 8;
    const int k0 = (slot % 8) << 7;
    const int b = bh / H_, h = bh % H_;
    const u16* qbase = qk + (size_t)b * 1024 * 1536 + h * 64;
    const u16* kbase = qbase + 768;
    const u16* qtg = qkT + ((size_t)bh * 2 + 0) * 64 * 1024;   // Q^T [y][1024]
    __shared__ __align__(16) u16 KB[2][8192];   // per buf: Qn [0,4096) | Qt [4096,8192)
    __shared__ __align__(16) u16 Ps[8192];
    const int t = threadIdx.x, w = t >> 6, l = t & 63, g = l >> 4, cid = l & 15;
    const int lr = l & 15, lc = l >> 4;

    #pragma unroll
    for (int h2 = 0; h2 < 2; ++h2)
        #pragma unroll
        for (int ch = 0; ch < 2; ++ch)
            gl2lds16(&kbase[(size_t)(k0 + 32 * w + 16 * h2 + lr) * 1536 + 32 * ch + 8 * lc],
                     &KB[0][(128 * (2 * w + h2) + 64 * ch + l) * 8]);
    __syncthreads();
    bf16x8 KF[2][2];
    #pragma unroll
    for (int jj = 0; jj < 2; ++jj)
        #pragma unroll
        for (int hh = 0; hh < 2; ++hh)
            KF[jj][hh] = *(const bf16x8*)&KB[0][(128 * (2 * w + jj) + 64 * hh + l) * 8];
    __syncthreads();

    auto stageQ = [&](int buf, int qt) {   // 4 gl2lds per wave
        #pragma unroll
        for (int ch = 0; ch < 2; ++ch) {
            gl2lds16(&qbase[(size_t)(qt * 64 + 16 * w + lr) * 1536 + 32 * ch + 8 * lc],
                     &KB[buf][(128 * w + 64 * ch + l) * 8]);
            gl2lds16(&qtg[(size_t)(16 * w + lr) * 1024 + qt * 64 + 32 * ch + 8 * lc],
                     &KB[buf][4096 + (128 * w + 64 * ch + l) * 8]);
        }
    };

    f32x4 acc[2][4] = {};
    stageQ(0, 0); stageQ(1, 1);
    #pragma unroll 1
    for (int qt = 0; qt < 16; ++qt) {
        if (qt == 15) { WAIT_VM(0); } else { WAIT_VM(4); }
        RAW_BARRIER();
        const int buf = qt & 1;
        const u16* Qn = &KB[buf][0];
        const u16* Qt = &KB[buf][4096];
        #pragma unroll
        for (int i = 0; i < 4; ++i) {
            bf16x8 a0 = *(const bf16x8*)&Qn[(128 * i + l) * 8];
            bf16x8 a1 = *(const bf16x8*)&Qn[(128 * i + 64 + l) * 8];
            f32x4 lv = *(const f32x4*)&L[(size_t)bh * 1024 + qt * 64 + 16 * i + 4 * g];
            #pragma unroll
            for (int jj = 0; jj < 2; ++jj) {
                f32x4 z = {0.f, 0.f, 0.f, 0.f};
                z = MFMA(a0, KF[jj][0], z, 0, 0, 0);
                z = MFMA(a1, KF[jj][1], z, 0, 0, 0);
                u16x4 pv;
                #pragma unroll
                for (int r = 0; r < 4; ++r)
                    pv[r] = f2bf(__expf(fmaf(z[r], BETA_, -lv[r])));
                *(u16x4*)&Ps[(128 * (2 * w + jj) + 32 * i + 16 * (g >> 1) + cid) * 8 + 4 * (g & 1)] = pv;
            }
        }
        #pragma unroll
        for (int jj = 0; jj < 2; ++jj) {
            bf16x8 p0 = *(const bf16x8*)&Ps[(128 * (2 * w + jj) + l) * 8];
            bf16x8 p1 = *(const bf16x8*)&Ps[(128 * (2 * w + jj) + 64 + l) * 8];
            #pragma unroll
            for (int j = 0; j < 4; ++j) {
                acc[jj][j] = MFMA(p0, *(const bf16x8*)&Qt[(128 * j + l) * 8], acc[jj][j], 0, 0, 0);
                acc[jj][j] = MFMA(p1, *(const bf16x8*)&Qt[(128 * j + 64 + l) * 8], acc[jj][j], 0, 0, 0);
            }
        }
        RAW_BARRIER();
        if (qt + 2 < 16) stageQ(buf, qt + 2);
    }
    #pragma unroll
    for (int jj = 0; jj < 2; ++jj)
        #pragma unroll
        for (int r = 0; r < 4; ++r) {
            int row = k0 + 32 * w + 16 * jj + 4 * g + r;
            #pragma unroll
            for (int j = 0; j < 4; ++j)
                mid[(size_t)(b * 1024 + row) * 4608 + 768 + h * 64 + 16 * j + cid] = f2bf(acc[jj][j][r]);
        }
}

// ---------------------------------------------------------------------------
extern "C" void kernel_launch(void* const* d_in, const int* in_sizes, int n_in,
                              void* d_out, int out_size, void* d_ws, size_t ws_size,
                              hipStream_t stream)
{
    const float* x     = (const float*)d_in[0];
    const float* gamma = (const float*)d_in[1];
    const float* betap = (const float*)d_in[2];
    const float* Wq    = (const float*)d_in[3];
    const float* Wk    = (const float*)d_in[4];
    const float* xi    = (const float*)d_in[5];
    float* xc = (float*)d_out;

    char* p = (char*)d_ws;
    u16* wcat_bf  = (u16*)p; p += (size_t)4608 * 768 * 2;   // [Wq;Wk;xi] rows
    u16* wcatT_bf = (u16*)p; p += (size_t)768 * 4608 * 2;
    u16* g_bf     = (u16*)p; p += (size_t)NTOK * 768 * 2;
    u16* qk_bf    = (u16*)p; p += (size_t)NTOK * 1536 * 2;
    u16* qkT_bf   = (u16*)p; p += (size_t)96 * 2 * 64 * 1024 * 2;
    u16* mid_bf   = (u16*)p; p += (size_t)NTOK * 4608 * 2;
    u16* part     = (u16*)p; p += (size_t)2 * NTOK * 768 * 2;   // bf16 partials
    float* L      = (float*)p; p += (size_t)96 * 1024 * 4;
    (void)ws_size; (void)in_sizes; (void)n_in; (void)out_size;

    hipMemcpyAsync(xc, x, (size_t)NTOK * 768 * 4, hipMemcpyDeviceToDevice, stream);

    convert_bf<<<576, 256, 0, stream>>>(Wq, wcat_bf, 147456);
    convert_bf<<<576, 256, 0, stream>>>(Wk, wcat_bf + 768 * 768, 147456);
    convert_bf<<<2304, 256, 0, stream>>>(xi, wcat_bf + 2 * 768 * 768, 589824);
    transpose_bf<<<dim3(72, 12), 256, 0, stream>>>(Wq, Wk, xi, wcatT_bf);

    // g_0 = LN(x)
    ln_kernel<<<NTOK, 256, 0, stream>>>(x, gamma, betap, g_bf);

    for (int step = 0; step < STEPS_; ++step) {
        // fused: qk (+qkT) and relu-mid in one N=4608 GEMM (XCD-swizzled)
        gemm_fwd<<<2304, 256, 0, stream>>>(
            g_bf, wcat_bf, qk_bf, qkT_bf, mid_bf);
        // Aq (+L), Ak  (XCD-swizzled, ping-pong staged)
        dq_kernel<<<768, 256, 0, stream>>>(qk_bf, qkT_bf, L, mid_bf);
        dk_kernel<<<768, 256, 0, stream>>>(qk_bf, qkT_bf, L, mid_bf);
        // part[z] = mid . Wcat (K halves, bf16 partials, XCD-swizzled)
        gemm_upd<<<768, 256, 0, stream>>>(mid_bf, wcatT_bf, part);
        // xc += alpha*(P0+P1); g = LN(xc)   (fused)
        reduce_ln<<<NTOK, 192, 0, stream>>>(part, xc, gamma, betap, g_bf);
    }
}

// Round 12
// 3716.304 us; speedup vs baseline: 1.1192x; 1.0568x over previous
//
#include <hip/hip_runtime.h>
#include <math.h>

#define H_ 12
#define STEPS_ 12
#define ALPHA_ 0.1f
#define EPS_ 1e-5f
#define BETA_ 0.125f          // 1/sqrt(64)
#define NTOK 8192

typedef unsigned short u16;
typedef __attribute__((ext_vector_type(8))) u16 u16x8;
typedef __attribute__((ext_vector_type(4))) u16 u16x4;
typedef __attribute__((ext_vector_type(4))) float f32x4;
typedef __attribute__((ext_vector_type(8))) __bf16 bf16x8;

#define MFMA __builtin_amdgcn_mfma_f32_16x16x32_bf16

__device__ __forceinline__ u16 f2bf(float x) {
    unsigned u = __float_as_uint(x);
    u += 0x7FFFu + ((u >> 16) & 1u);
    return (u16)(u >> 16);
}
__device__ __forceinline__ float bf2f(u16 u) {
    return __uint_as_float(((unsigned)u) << 16);
}

// async global->LDS, 16B per lane; LDS dst is wave-uniform base + 16*lane
__device__ __forceinline__ void gl2lds16(const u16* gsrc, u16* ldst) {
    __builtin_amdgcn_global_load_lds(
        (const __attribute__((address_space(1))) void*)gsrc,
        (__attribute__((address_space(3))) void*)ldst, 16, 0, 0);
}

// raw barrier / waitcnt (no compiler-attached vmcnt(0) drain)
#define RAW_BARRIER()   asm volatile("s_barrier" ::: "memory")
#define WAIT_VM(n)      asm volatile("s_waitcnt vmcnt(" #n ")" ::: "memory")

// ---------------- initial LayerNorm x -> bf16 g (once, pre-loop) -----------
__global__ __launch_bounds__(256) void ln_kernel(const float* __restrict__ x,
    const float* __restrict__ gamma, const float* __restrict__ beta,
    u16* __restrict__ g)
{
    int row = blockIdx.x;
    const float* xr = x + (size_t)row * 768;
    u16* gr = g + (size_t)row * 768;
    int t = threadIdx.x;
    float v0 = xr[t], v1 = xr[t + 256], v2 = xr[t + 512];
    float s = v0 + v1 + v2;
    #pragma unroll
    for (int off = 32; off > 0; off >>= 1) s += __shfl_down(s, off);
    __shared__ float red[8];
    int wid = t >> 6, lane = t & 63;
    if (lane == 0) red[wid] = s;
    __syncthreads();
    if (t == 0) red[0] = (red[0] + red[1] + red[2] + red[3]) * (1.0f / 768.0f);
    __syncthreads();
    float mu = red[0];
    float d0 = v0 - mu, d1 = v1 - mu, d2 = v2 - mu;
    float ss = d0*d0 + d1*d1 + d2*d2;
    #pragma unroll
    for (int off = 32; off > 0; off >>= 1) ss += __shfl_down(ss, off);
    if (lane == 0) red[4 + wid] = ss;
    __syncthreads();
    if (t == 0) red[4] = rsqrtf((red[4] + red[5] + red[6] + red[7]) * (1.0f / 768.0f) + EPS_);
    __syncthreads();
    float rs = red[4];
    gr[t]       = f2bf(gamma[t]       * d0 * rs + beta[t]);
    gr[t + 256] = f2bf(gamma[t + 256] * d1 * rs + beta[t + 256]);
    gr[t + 512] = f2bf(gamma[t + 512] * d2 * rs + beta[t + 512]);
}

// ------- fused: xc += alpha*(P0+P1); g = LN(xc)  (one block per row) --------
__global__ __launch_bounds__(192) void reduce_ln(const u16* __restrict__ part,
    float* __restrict__ xc, const float* __restrict__ gamma,
    const float* __restrict__ beta, u16* __restrict__ g)
{
    int row = blockIdx.x, t = threadIdx.x;
    const u16x4* p0 = (const u16x4*)(part + (size_t)row * 768);
    const u16x4* p1 = (const u16x4*)(part + (size_t)(8192 + row) * 768);
    f32x4* xr = (f32x4*)(xc + (size_t)row * 768);
    f32x4 v = xr[t];
    u16x4 a = p0[t], b = p1[t];
    #pragma unroll
    for (int e = 0; e < 4; ++e) v[e] = fmaf(ALPHA_, bf2f(a[e]) + bf2f(b[e]), v[e]);
    xr[t] = v;
    float s = (v[0] + v[1]) + (v[2] + v[3]);
    #pragma unroll
    for (int off = 32; off > 0; off >>= 1) s += __shfl_down(s, off);
    __shared__ float red[8];
    int wid = t >> 6, lane = t & 63;
    if (lane == 0) red[wid] = s;
    __syncthreads();
    if (t == 0) red[0] = (red[0] + red[1] + red[2]) * (1.0f / 768.0f);
    __syncthreads();
    float mu = red[0];
    f32x4 d;
    #pragma unroll
    for (int e = 0; e < 4; ++e) d[e] = v[e] - mu;
    float ss = (d[0]*d[0] + d[1]*d[1]) + (d[2]*d[2] + d[3]*d[3]);
    #pragma unroll
    for (int off = 32; off > 0; off >>= 1) ss += __shfl_down(ss, off);
    if (lane == 0) red[4 + wid] = ss;
    __syncthreads();
    if (t == 0) red[4] = rsqrtf((red[4] + red[5] + red[6]) * (1.0f / 768.0f) + EPS_);
    __syncthreads();
    float rs = red[4];
    const f32x4 gm = *(const f32x4*)&gamma[t * 4];
    const f32x4 bt = *(const f32x4*)&beta[t * 4];
    u16x4 o;
    #pragma unroll
    for (int e = 0; e < 4; ++e) o[e] = f2bf(fmaf(gm[e], d[e] * rs, bt[e]));
    *(u16x4*)&g[(size_t)row * 768 + t * 4] = o;
}

// ---------------- fp32 -> bf16 convert ----------------
__global__ __launch_bounds__(256) void convert_bf(const float* __restrict__ src,
                                                  u16* __restrict__ dst, int n4)
{
    int i = blockIdx.x * 256 + threadIdx.x;
    if (i < n4) {
        f32x4 v = *(const f32x4*)&src[i * 4];
        u16x4 o;
        #pragma unroll
        for (int e = 0; e < 4; ++e) o[e] = f2bf(v[e]);
        *(u16x4*)&dst[i * 4] = o;
    }
}

// -------- transpose-convert: Wcat [4608x768] f32 -> WcatT [768x4608] bf16 ----
__global__ __launch_bounds__(256) void transpose_bf(const float* __restrict__ Wq,
    const float* __restrict__ Wk, const float* __restrict__ xi, u16* __restrict__ out)
{
    __shared__ float tile[64][65];
    int rb = blockIdx.x * 64, cb = blockIdx.y * 64;
    const float* src;
    if (rb < 768) src = Wq + (size_t)rb * 768;
    else if (rb < 1536) src = Wk + (size_t)(rb - 768) * 768;
    else src = xi + (size_t)(rb - 1536) * 768;
    int t = threadIdx.x;
    #pragma unroll
    for (int it = 0; it < 4; ++it) {
        int r = (t >> 4) + 16 * it;
        f32x4 v = *(const f32x4*)&src[(size_t)r * 768 + cb + (t & 15) * 4];
        #pragma unroll
        for (int e = 0; e < 4; ++e) tile[r][(t & 15) * 4 + e] = v[e];
    }
    __syncthreads();
    #pragma unroll
    for (int it = 0; it < 4; ++it) {
        int cl = (t >> 4) + 16 * it;
        u16x4 o;
        #pragma unroll
        for (int e = 0; e < 4; ++e) o[e] = f2bf(tile[(t & 15) * 4 + e][cl]);
        *(u16x4*)&out[(size_t)(cb + cl) * 4608 + rb + (t & 15) * 4] = o;
    }
}

// ---------------- fused fwd GEMM: [qk | relu-mid] = g . Wcat^T --------------
// 256x128 tile, 512 threads (8 waves, 4x2 of 64x64), BK=32, 2-stage ping-pong
// + dual raw barriers, static addressing. Taller tile: staged bytes/FLOP
// -25% vs 128x128, TLP ~16 waves/CU. XCD-swizzled 1-D grid 1152
// (n-outer / m-inner per XCD; per-XCD A-slab 1024 rows = 1.57 MB L2-hot).
__global__ __launch_bounds__(512) void gemm_fwd(
    const u16* __restrict__ A,      // g [8192 x 768]
    const u16* __restrict__ Bt,     // Wcat rows [4608 x 768] (Wq|Wk|xi)
    u16* __restrict__ qkb, u16* __restrict__ qkT, u16* __restrict__ midb)
{
    // per buffer: A panel [0, 8192) u16 (256 rows x 32 k), B panel [8192, 12288)
    __shared__ __align__(16) u16 S[2][12288];
    const int t = threadIdx.x, w = t >> 6, l = t & 63, g = l >> 4, cid = l & 15;
    const int lr = l & 15, lc = l >> 4;
    const int flat = blockIdx.x;
    const int xcd = flat & 7, slot = flat >> 3;   // 144 slots per XCD
    const int nid = slot / 4, mloc = slot % 4;    // n-outer, m-inner
    const int bm = (xcd * 4 + mloc) * 256;        // 32 m-tiles
    const int bn = nid * 128;                     // 36 n-tiles
    const int RO = (w >> 1) * 64, CO = (w & 1) * 64;
    f32x4 acc[4][4] = {};

    // 24 staging chunks (16 A + 8 B), 3 per wave; wave-uniform chunk ids
    const u16* gp[3];
    int ld[3];
    #pragma unroll
    for (int j = 0; j < 3; ++j) {
        int c = 3 * w + j;
        if (c < 16) {
            gp[j] = A + (size_t)(bm + 16 * c + lr) * 768 + 8 * lc;
            ld[j] = (64 * c + l) * 8;
        } else {
            gp[j] = Bt + (size_t)(bn + 16 * (c - 16) + lr) * 768 + 8 * lc;
            ld[j] = 8192 + (64 * (c - 16) + l) * 8;
        }
    }

    auto stage = [&](int buf, int off) {   // 3 gl2lds per wave
        #pragma unroll
        for (int j = 0; j < 3; ++j)
            gl2lds16(gp[j] + off, &S[buf][ld[j]]);
    };
    auto compute = [&](int buf) {
        bf16x8 af[4], bfr[4];
        #pragma unroll
        for (int i = 0; i < 4; ++i) af[i]  = *(const bf16x8*)&S[buf][(64 * ((RO >> 4) + i) + l) * 8];
        #pragma unroll
        for (int j = 0; j < 4; ++j) bfr[j] = *(const bf16x8*)&S[buf][8192 + (64 * ((CO >> 4) + j) + l) * 8];
        #pragma unroll
        for (int i = 0; i < 4; ++i)
            #pragma unroll
            for (int j = 0; j < 4; ++j)
                acc[i][j] = MFMA(af[i], bfr[j], acc[i][j], 0, 0, 0);
    };
    auto adv = [&]() { gp[0] += 64; gp[1] += 64; gp[2] += 64; };

    stage(0, 0); stage(1, 32);
    #pragma unroll 1
    for (int ii = 0; ii < 11; ++ii) {
        WAIT_VM(3); RAW_BARRIER(); compute(0); RAW_BARRIER(); stage(0, 64);
        WAIT_VM(3); RAW_BARRIER(); compute(1); RAW_BARRIER(); stage(1, 96);
        adv();
    }
    WAIT_VM(3); RAW_BARRIER(); compute(0);
    WAIT_VM(0); RAW_BARRIER(); compute(1);

    if (bn < 1536) {
        int bidx = bm >> 10;
        #pragma unroll
        for (int i = 0; i < 4; ++i) {
            int tok = bm + RO + 16 * i + 4 * g;
            #pragma unroll
            for (int j = 0; j < 4; ++j) {
                int col = bn + CO + 16 * j + cid;
                int sel = col >= 768 ? 1 : 0;
                int cc = col - 768 * sel;
                int hh = cc >> 6, yy = cc & 63;
                u16x4 tv;
                #pragma unroll
                for (int r = 0; r < 4; ++r) {
                    u16 bv = f2bf(acc[i][j][r]);
                    tv[r] = bv;
                    qkb[(size_t)(tok + r) * 1536 + col] = bv;
                }
                *(u16x4*)&qkT[((((size_t)bidx * 12 + hh) * 2 + sel) * 64 + yy) * 1024 + (tok & 1023)] = tv;
            }
        }
    } else {
        #pragma unroll
        for (int i = 0; i < 4; ++i)
            #pragma unroll
            for (int r = 0; r < 4; ++r) {
                size_t row = bm + RO + 16 * i + 4 * g + r;
                #pragma unroll
                for (int j = 0; j < 4; ++j) {
                    int col = bn + CO + 16 * j + cid;
                    midb[row * 4608 + col] = f2bf(fmaxf(acc[i][j][r], 0.0f));
                }
            }
    }
}

// ------- update GEMM: part[z] = mid . WcatT (K-half z), bf16 partials -------
__global__ __launch_bounds__(256, 4) void gemm_upd(
    const u16* __restrict__ A,      // mid [8192 x 4608]
    const u16* __restrict__ Bt,     // WcatT [768 x 4608]
    u16* __restrict__ part)         // [2][8192][768] bf16
{
    __shared__ __align__(16) u16 As[2][4096];
    __shared__ __align__(16) u16 Bs[2][4096];
    const int t = threadIdx.x, w = t >> 6, l = t & 63, g = l >> 4, cid = l & 15;
    const int lr = l & 15, lc = l >> 4;
    const int flat = blockIdx.x;
    const int xcd = flat & 7, slot = flat >> 3;        // 96 slots per XCD
    const int z = slot / 48, rem = slot % 48;
    const int mloc = rem / 6, n = rem % 6;
    const int bm = ((xcd << 3) + mloc) * 128, bn = n * 128;
    const int kbeg = z * 2304;
    const int RO = (w >> 1) * 64, CO = (w & 1) * 64;
    u16* out = part + (size_t)z * 8192 * 768;
    f32x4 acc[4][4] = {};

    const u16* ga0 = A  + (size_t)(bm + 32 * w + lr) * 4608 + kbeg + 8 * lc;
    const u16* ga1 = A  + (size_t)(bm + 32 * w + 16 + lr) * 4608 + kbeg + 8 * lc;
    const u16* gb0 = Bt + (size_t)(bn + 32 * w + lr) * 4608 + kbeg + 8 * lc;
    const u16* gb1 = Bt + (size_t)(bn + 32 * w + 16 + lr) * 4608 + kbeg + 8 * lc;

    auto stage = [&](int buf, int off) {
        gl2lds16(ga0 + off, &As[buf][(64 * (2 * w + 0) + l) * 8]);
        gl2lds16(ga1 + off, &As[buf][(64 * (2 * w + 1) + l) * 8]);
        gl2lds16(gb0 + off, &Bs[buf][(64 * (2 * w + 0) + l) * 8]);
        gl2lds16(gb1 + off, &Bs[buf][(64 * (2 * w + 1) + l) * 8]);
    };
    auto compute = [&](int buf) {
        bf16x8 af[4], bfr[4];
        #pragma unroll
        for (int i = 0; i < 4; ++i) af[i]  = *(const bf16x8*)&As[buf][(64 * ((RO >> 4) + i) + l) * 8];
        #pragma unroll
        for (int j = 0; j < 4; ++j) bfr[j] = *(const bf16x8*)&Bs[buf][(64 * ((CO >> 4) + j) + l) * 8];
        #pragma unroll
        for (int i = 0; i < 4; ++i)
            #pragma unroll
            for (int j = 0; j < 4; ++j)
                acc[i][j] = MFMA(af[i], bfr[j], acc[i][j], 0, 0, 0);
    };
    auto adv = [&]() { ga0 += 64; ga1 += 64; gb0 += 64; gb1 += 64; };

    stage(0, 0); stage(1, 32);
    #pragma unroll 1
    for (int ii = 0; ii < 35; ++ii) {
        WAIT_VM(4); RAW_BARRIER(); compute(0); RAW_BARRIER(); stage(0, 64);
        WAIT_VM(4); RAW_BARRIER(); compute(1); RAW_BARRIER(); stage(1, 96);
        adv();
    }
    WAIT_VM(4); RAW_BARRIER(); compute(0);
    WAIT_VM(0); RAW_BARRIER(); compute(1);

    #pragma unroll
    for (int i = 0; i < 4; ++i)
        #pragma unroll
        for (int r = 0; r < 4; ++r) {
            size_t row = bm + RO + 16 * i + 4 * g + r;
            #pragma unroll
            for (int j = 0; j < 4; ++j)
                out[row * 768 + bn + CO + 16 * j + cid] = f2bf(acc[i][j][r]);
        }
}

// ---------------- dq: flash pass over k, 128-q tile, computes L and Aq -------
// Ping-pong staging via dead-slab aliasing (R11). XCD-swizzled grid 768.
__global__ __launch_bounds__(256) void dq_kernel(const u16* __restrict__ qk,
    const u16* __restrict__ qkT, float* __restrict__ L, u16* __restrict__ mid)
{
    const int flat = blockIdx.x;
    const int xcd = flat & 7, slot = flat >> 3;       // 96 slots per XCD
    const int bh = xcd * 12 + slot / 8;               // 12 bh per XCD
    const int q0 = (slot % 8) << 7;
    const int b = bh / H_, h = bh % H_;
    const u16* qbase = qk + (size_t)b * 1024 * 1536 + h * 64;
    const u16* kbase = qbase + 768;
    const u16* ktg = qkT + ((size_t)bh * 2 + 1) * 64 * 1024;   // K^T [y][1024]
    __shared__ __align__(16) u16 KB[2][8192];   // per buf: Kn [0,4096) | Kt [4096,8192)
    __shared__ __align__(16) u16 Ps[8192];
    const int t = threadIdx.x, w = t >> 6, l = t & 63, g = l >> 4, cid = l & 15;
    const int lr = l & 15, lc = l >> 4;

    #pragma unroll
    for (int h2 = 0; h2 < 2; ++h2)
        #pragma unroll
        for (int ch = 0; ch < 2; ++ch)
            gl2lds16(&qbase[(size_t)(q0 + 32 * w + 16 * h2 + lr) * 1536 + 32 * ch + 8 * lc],
                     &KB[0][(128 * (2 * w + h2) + 64 * ch + l) * 8]);
    __syncthreads();
    bf16x8 QF[2][2];
    #pragma unroll
    for (int jj = 0; jj < 2; ++jj)
        #pragma unroll
        for (int hh = 0; hh < 2; ++hh)
            QF[jj][hh] = *(const bf16x8*)&KB[0][(128 * (2 * w + jj) + 64 * hh + l) * 8];
    __syncthreads();   // all QF reads done before KB[0] is restaged

    auto stageK = [&](int buf, int kt) {   // 4 gl2lds per wave
        #pragma unroll
        for (int ch = 0; ch < 2; ++ch) {
            gl2lds16(&kbase[(size_t)(kt * 64 + 16 * w + lr) * 1536 + 32 * ch + 8 * lc],
                     &KB[buf][(128 * w + 64 * ch + l) * 8]);
            gl2lds16(&ktg[(size_t)(16 * w + lr) * 1024 + kt * 64 + 32 * ch + 8 * lc],
                     &KB[buf][4096 + (128 * w + 64 * ch + l) * 8]);
        }
    };

    f32x4 acc[2][4] = {};
    float lrun[2] = {0.0f, 0.0f};

    stageK(0, 0); stageK(1, 1);
    #pragma unroll 1
    for (int kt = 0; kt < 16; ++kt) {
        if (kt == 15) { WAIT_VM(0); } else { WAIT_VM(4); }
        RAW_BARRIER();
        const int buf = kt & 1;
        const u16* Kn = &KB[buf][0];
        const u16* Kt = &KB[buf][4096];
        f32x4 s[4][2];
        #pragma unroll
        for (int i = 0; i < 4; ++i) {
            bf16x8 a0 = *(const bf16x8*)&Kn[(128 * i + l) * 8];
            bf16x8 a1 = *(const bf16x8*)&Kn[(128 * i + 64 + l) * 8];
            #pragma unroll
            for (int jj = 0; jj < 2; ++jj) {
                f32x4 z = {0.f, 0.f, 0.f, 0.f};
                z = MFMA(a0, QF[jj][0], z, 0, 0, 0);
                z = MFMA(a1, QF[jj][1], z, 0, 0, 0);
                s[i][jj] = z;
            }
        }
        #pragma unroll
        for (int jj = 0; jj < 2; ++jj) {
            float psum = 0.0f;
            #pragma unroll
            for (int i = 0; i < 4; ++i) {
                u16x4 pv;
                #pragma unroll
                for (int r = 0; r < 4; ++r) {
                    float p = __expf(s[i][jj][r] * BETA_);
                    psum += p;
                    pv[r] = f2bf(p);
                }
                *(u16x4*)&Ps[(128 * (2 * w + jj) + 32 * i + 16 * (g >> 1) + cid) * 8 + 4 * (g & 1)] = pv;
            }
            psum += __shfl_xor(psum, 16);
            psum += __shfl_xor(psum, 32);
            lrun[jj] += psum;
        }
        #pragma unroll
        for (int jj = 0; jj < 2; ++jj) {
            bf16x8 p0 = *(const bf16x8*)&Ps[(128 * (2 * w + jj) + l) * 8];
            bf16x8 p1 = *(const bf16x8*)&Ps[(128 * (2 * w + jj) + 64 + l) * 8];
            #pragma unroll
            for (int j = 0; j < 4; ++j) {
                acc[jj][j] = MFMA(p0, *(const bf16x8*)&Kt[(128 * j + l) * 8], acc[jj][j], 0, 0, 0);
                acc[jj][j] = MFMA(p1, *(const bf16x8*)&Kt[(128 * j + 64 + l) * 8], acc[jj][j], 0, 0, 0);
            }
        }
        RAW_BARRIER();
        if (kt + 2 < 16) stageK(buf, kt + 2);
    }
    #pragma unroll
    for (int jj = 0; jj < 2; ++jj) {
        if (g == 0)
            L[(size_t)bh * 1024 + q0 + 32 * w + 16 * jj + cid] = __logf(lrun[jj]);
        float linv = 1.0f / lrun[jj];
        #pragma unroll
        for (int r = 0; r < 4; ++r) {
            float fr = __shfl(linv, 4 * g + r);
            int row = q0 + 32 * w + 16 * jj + 4 * g + r;
            #pragma unroll
            for (int j = 0; j < 4; ++j)
                mid[(size_t)(b * 1024 + row) * 4608 + h * 64 + 16 * j + cid] = f2bf(acc[jj][j][r] * fr);
        }
    }
}

// ---------------- dk: Ak[k] = sum_q exp(beta*S - L[q]) q, 128-k tile --------
__global__ __launch_bounds__(256) void dk_kernel(const u16* __restrict__ qk,
    const u16* __restrict__ qkT, const float* __restrict__ L, u16* __restrict__ mid)
{
    const int flat = blockIdx.x;
    const int xcd = flat & 7, slot = flat >> 3;
    const int bh = xcd * 12 + slot / 8;
    const int k0 = (slot % 8) << 7;
    const int b = bh / H_, h = bh % H_;
    const u16* qbase = qk + (size_t)b * 1024 * 1536 + h * 64;
    const u16* kbase = qbase + 768;
    const u16* qtg = qkT + ((size_t)bh * 2 + 0) * 64 * 1024;   // Q^T [y][1024]
    __shared__ __align__(16) u16 KB[2][8192];   // per buf: Qn [0,4096) | Qt [4096,8192)
    __shared__ __align__(16) u16 Ps[8192];
    const int t = threadIdx.x, w = t >> 6, l = t & 63, g = l >> 4, cid = l & 15;
    const int lr = l & 15, lc = l >> 4;

    #pragma unroll
    for (int h2 = 0; h2 < 2; ++h2)
        #pragma unroll
        for (int ch = 0; ch < 2; ++ch)
            gl2lds16(&kbase[(size_t)(k0 + 32 * w + 16 * h2 + lr) * 1536 + 32 * ch + 8 * lc],
                     &KB[0][(128 * (2 * w + h2) + 64 * ch + l) * 8]);
    __syncthreads();
    bf16x8 KF[2][2];
    #pragma unroll
    for (int jj = 0; jj < 2; ++jj)
        #pragma unroll
        for (int hh = 0; hh < 2; ++hh)
            KF[jj][hh] = *(const bf16x8*)&KB[0][(128 * (2 * w + jj) + 64 * hh + l) * 8];
    __syncthreads();

    auto stageQ = [&](int buf, int qt) {   // 4 gl2lds per wave
        #pragma unroll
        for (int ch = 0; ch < 2; ++ch) {
            gl2lds16(&qbase[(size_t)(qt * 64 + 16 * w + lr) * 1536 + 32 * ch + 8 * lc],
                     &KB[buf][(128 * w + 64 * ch + l) * 8]);
            gl2lds16(&qtg[(size_t)(16 * w + lr) * 1024 + qt * 64 + 32 * ch + 8 * lc],
                     &KB[buf][4096 + (128 * w + 64 * ch + l) * 8]);
        }
    };

    f32x4 acc[2][4] = {};
    stageQ(0, 0); stageQ(1, 1);
    #pragma unroll 1
    for (int qt = 0; qt < 16; ++qt) {
        if (qt == 15) { WAIT_VM(0); } else { WAIT_VM(4); }
        RAW_BARRIER();
        const int buf = qt & 1;
        const u16* Qn = &KB[buf][0];
        const u16* Qt = &KB[buf][4096];
        #pragma unroll
        for (int i = 0; i < 4; ++i) {
            bf16x8 a0 = *(const bf16x8*)&Qn[(128 * i + l) * 8];
            bf16x8 a1 = *(const bf16x8*)&Qn[(128 * i + 64 + l) * 8];
            f32x4 lv = *(const f32x4*)&L[(size_t)bh * 1024 + qt * 64 + 16 * i + 4 * g];
            #pragma unroll
            for (int jj = 0; jj < 2; ++jj) {
                f32x4 z = {0.f, 0.f, 0.f, 0.f};
                z = MFMA(a0, KF[jj][0], z, 0, 0, 0);
                z = MFMA(a1, KF[jj][1], z, 0, 0, 0);
                u16x4 pv;
                #pragma unroll
                for (int r = 0; r < 4; ++r)
                    pv[r] = f2bf(__expf(fmaf(z[r], BETA_, -lv[r])));
                *(u16x4*)&Ps[(128 * (2 * w + jj) + 32 * i + 16 * (g >> 1) + cid) * 8 + 4 * (g & 1)] = pv;
            }
        }
        #pragma unroll
        for (int jj = 0; jj < 2; ++jj) {
            bf16x8 p0 = *(const bf16x8*)&Ps[(128 * (2 * w + jj) + l) * 8];
            bf16x8 p1 = *(const bf16x8*)&Ps[(128 * (2 * w + jj) + 64 + l) * 8];
            #pragma unroll
            for (int j = 0; j < 4; ++j) {
                acc[jj][j] = MFMA(p0, *(const bf16x8*)&Qt[(128 * j + l) * 8], acc[jj][j], 0, 0, 0);
                acc[jj][j] = MFMA(p1, *(const bf16x8*)&Qt[(128 * j + 64 + l) * 8], acc[jj][j], 0, 0, 0);
            }
        }
        RAW_BARRIER();
        if (qt + 2 < 16) stageQ(buf, qt + 2);
    }
    #pragma unroll
    for (int jj = 0; jj < 2; ++jj)
        #pragma unroll
        for (int r = 0; r < 4; ++r) {
            int row = k0 + 32 * w + 16 * jj + 4 * g + r;
            #pragma unroll
            for (int j = 0; j < 4; ++j)
                mid[(size_t)(b * 1024 + row) * 4608 + 768 + h * 64 + 16 * j + cid] = f2bf(acc[jj][j][r]);
        }
}

// ---------------------------------------------------------------------------
extern "C" void kernel_launch(void* const* d_in, const int* in_sizes, int n_in,
                              void* d_out, int out_size, void* d_ws, size_t ws_size,
                              hipStream_t stream)
{
    const float* x     = (const float*)d_in[0];
    const float* gamma = (const float*)d_in[1];
    const float* betap = (const float*)d_in[2];
    const float* Wq    = (const float*)d_in[3];
    const float* Wk    = (const float*)d_in[4];
    const float* xi    = (const float*)d_in[5];
    float* xc = (float*)d_out;

    char* p = (char*)d_ws;
    u16* wcat_bf  = (u16*)p; p += (size_t)4608 * 768 * 2;   // [Wq;Wk;xi] rows
    u16* wcatT_bf = (u16*)p; p += (size_t)768 * 4608 * 2;
    u16* g_bf     = (u16*)p; p += (size_t)NTOK * 768 * 2;
    u16* qk_bf    = (u16*)p; p += (size_t)NTOK * 1536 * 2;
    u16* qkT_bf   = (u16*)p; p += (size_t)96 * 2 * 64 * 1024 * 2;
    u16* mid_bf   = (u16*)p; p += (size_t)NTOK * 4608 * 2;
    u16* part     = (u16*)p; p += (size_t)2 * NTOK * 768 * 2;   // bf16 partials
    float* L      = (float*)p; p += (size_t)96 * 1024 * 4;
    (void)ws_size; (void)in_sizes; (void)n_in; (void)out_size;

    hipMemcpyAsync(xc, x, (size_t)NTOK * 768 * 4, hipMemcpyDeviceToDevice, stream);

    convert_bf<<<576, 256, 0, stream>>>(Wq, wcat_bf, 147456);
    convert_bf<<<576, 256, 0, stream>>>(Wk, wcat_bf + 768 * 768, 147456);
    convert_bf<<<2304, 256, 0, stream>>>(xi, wcat_bf + 2 * 768 * 768, 589824);
    transpose_bf<<<dim3(72, 12), 256, 0, stream>>>(Wq, Wk, xi, wcatT_bf);

    // g_0 = LN(x)
    ln_kernel<<<NTOK, 256, 0, stream>>>(x, gamma, betap, g_bf);

    for (int step = 0; step < STEPS_; ++step) {
        // fused: qk (+qkT) and relu-mid in one N=4608 GEMM (256x128 tiles)
        gemm_fwd<<<1152, 512, 0, stream>>>(
            g_bf, wcat_bf, qk_bf, qkT_bf, mid_bf);
        // Aq (+L), Ak  (XCD-swizzled, ping-pong staged)
        dq_kernel<<<768, 256, 0, stream>>>(qk_bf, qkT_bf, L, mid_bf);
        dk_kernel<<<768, 256, 0, stream>>>(qk_bf, qkT_bf, L, mid_bf);
        // part[z] = mid . Wcat (K halves, bf16 partials, XCD-swizzled)
        gemm_upd<<<768, 256, 0, stream>>>(mid_bf, wcatT_bf, part);
        // xc += alpha*(P0+P1); g = LN(xc)   (fused)
        reduce_ln<<<NTOK, 192, 0, stream>>>(part, xc, gamma, betap, g_bf);
    }
}